// Round 1
// baseline (885.773 us; speedup 1.0000x reference)
//
#include <hip/hip_runtime.h>

// ---------------------------------------------------------------------------
// SelfAttention block-sparse value aggregation, fully fused, bf16 MFMA.
// B=8, H=W=128, E=256, VD=256, nh=8, vhd=32, bs=8 (bs2=64), topk=16.
// One workgroup (256 thr = 4 waves) per (batch, block) tile; 2048 WGs.
// LDS: XPT[256 cols][104 tokens] bf16 (52KB, stride 208B); attention output
// is written back into the same region per-head (head h region at byte
// 6656*h, row stride 80B) after that head's reads complete (same wave).
// ---------------------------------------------------------------------------

typedef __attribute__((ext_vector_type(4))) float   f32x4;
typedef __attribute__((ext_vector_type(8))) __bf16  bf16x8;
typedef __attribute__((ext_vector_type(4))) __bf16  bf16x4;
typedef __attribute__((ext_vector_type(8))) unsigned short u16x8;

#define XPT_STRIDE 208   // bytes per XPT row (104 bf16 elems)
#define REG_SIZE   6656  // bytes per head ATT region (= 32*XPT_STRIDE)
#define REG_STRIDE 80    // bytes per ATT region row (40 bf16 elems)
#define LDS_BYTES  53248 // 256 * 208

__global__ void prep_weights_k(const float* __restrict__ Wi,
                               const float* __restrict__ Wo,
                               __bf16* __restrict__ WiT,
                               __bf16* __restrict__ WoT) {
    int n = blockIdx.x;   // 256
    int k = threadIdx.x;  // 256
    WiT[n * 256 + k] = (__bf16)Wi[k * 256 + n];   // WiT[n][k] = W_in[k][n]
    WoT[n * 256 + k] = (__bf16)Wo[k * 256 + n];   // WoT[e][c] = W_out[c][e]
}

__device__ __forceinline__ bf16x8 cvt8(f32x4 lo, f32x4 hi) {
    bf16x8 r;
    r[0] = (__bf16)lo.x; r[1] = (__bf16)lo.y; r[2] = (__bf16)lo.z; r[3] = (__bf16)lo.w;
    r[4] = (__bf16)hi.x; r[5] = (__bf16)hi.y; r[6] = (__bf16)hi.z; r[7] = (__bf16)hi.w;
    return r;
}

__global__ __launch_bounds__(256, 3) void fused_attn_k(
    const float* __restrict__ x,     // (8,128,128,256) f32
    const float* __restrict__ aw,    // (8,8,256,64,80) f32
    const int*   __restrict__ idx,   // (8,256,16) i32
    const float* __restrict__ wts,   // (8,256,16) f32
    const float* __restrict__ b_in,  // (256) f32
    const float* __restrict__ b_out, // (256) f32
    const __bf16* __restrict__ WiT,  // (256,256) bf16 [n][k]
    const __bf16* __restrict__ WoT,  // (256,256) bf16 [e][c]
    float* __restrict__ out)         // (8,128,128,256) f32
{
    __shared__ __align__(16) unsigned char lds[LDS_BYTES];

    const int tid  = threadIdx.x;
    const int lane = tid & 63;
    const int wv   = tid >> 6;       // 0..3
    const int l16  = lane & 15;
    const int q    = lane >> 4;      // 0..3
    const int bid  = blockIdx.x;
    const int b    = bid >> 8;       // batch
    const int blk  = bid & 255;      // block id
    const int bh   = blk >> 4, bw = blk & 15;
    const int nbase = wv * 64;       // this wave's vd-column quarter

    const float* xb   = x   + (size_t)b * 16384 * 256;
    const int*   idxb = idx + (b * 256 + blk) * 16;
    const float* wtsb = wts + (b * 256 + blk) * 16;

    // ---- zero pad tokens j = 80..95 of this wave's XPT rows (for K-pad) ----
    {
        int c = nbase + lane;
        u16x8 z = {0, 0, 0, 0, 0, 0, 0, 0};
        *(u16x8*)(lds + c * XPT_STRIDE + 160) = z;  // j 80..87
        *(u16x8*)(lds + c * XPT_STRIDE + 176) = z;  // j 88..95
    }

    // =========== Phase 1: XPT[c][j] = (x_row_j . W_in[:,c] + b_in[c]) * rs ==
    // M = 80 tokens (5 m-tiles), N = 64 cols/wave (4 n-tiles), K = 256 (8 ch)
    for (int mt = 0; mt < 5; ++mt) {
        // A-operand row for this lane: token m = mt*16 + l16
        int m = mt * 16 + l16;
        int tokA;
        if (m < 64) {
            tokA = ((bh << 3) + (m >> 3)) * 128 + (bw << 3) + (m & 7);
        } else {
            tokA = idxb[m - 64];
        }
        const float* xrow = xb + (size_t)tokA * 256;
        bf16x8 af[8];
        #pragma unroll
        for (int kc = 0; kc < 8; ++kc) {
            const f32x4* p = (const f32x4*)(xrow + kc * 32 + q * 8);
            af[kc] = cvt8(p[0], p[1]);
        }
        // row scales for the 4 C-frag rows (gathered tokens get their weight)
        float rs[4];
        #pragma unroll
        for (int r = 0; r < 4; ++r) {
            int me = mt * 16 + q * 4 + r;
            rs[r] = (me >= 64) ? wtsb[me - 64] : 1.0f;
        }
        const int j0w = mt * 16 + q * 4;  // epilogue token base
        #pragma unroll
        for (int n4 = 0; n4 < 4; ++n4) {
            int c = nbase + n4 * 16 + l16;
            f32x4 acc = {0.f, 0.f, 0.f, 0.f};
            const __bf16* wcol = WiT + c * 256 + q * 8;
            #pragma unroll
            for (int kc = 0; kc < 8; ++kc) {
                bf16x8 bfrag = *(const bf16x8*)(wcol + kc * 32);
                acc = __builtin_amdgcn_mfma_f32_16x16x32_bf16(af[kc], bfrag, acc, 0, 0, 0);
            }
            float bias = b_in[c];
            bf16x4 w4;
            #pragma unroll
            for (int r = 0; r < 4; ++r)
                w4[r] = (__bf16)((acc[r] + bias) * rs[r]);
            // XPT[c][j0w .. j0w+3]
            *(bf16x4*)(lds + c * XPT_STRIDE + j0w * 2) = w4;
        }
    }

    // =========== Phase 2: attention, transposed: OUT^T[d][i] ================
    // per head: M = d (32, 2 tiles), N = i (64, 4 tiles), K = j (80 pad 96)
    #pragma unroll
    for (int hh = 0; hh < 2; ++hh) {
        const int h = wv * 2 + hh;
        const float* awh = aw + ((size_t)(h * 8 + b) * 256 + blk) * (64 * 80);
        f32x4 acc[2][4];
        #pragma unroll
        for (int md = 0; md < 2; ++md)
            #pragma unroll
            for (int n4 = 0; n4 < 4; ++n4)
                acc[md][n4] = (f32x4){0.f, 0.f, 0.f, 0.f};

        #pragma unroll
        for (int n4 = 0; n4 < 4; ++n4) {
            int i = n4 * 16 + l16;  // B-frag column (query token)
            #pragma unroll
            for (int kc = 0; kc < 3; ++kc) {
                int j0 = kc * 32 + q * 8;
                // AW B-frag: aw[i][j0..j0+7]; clamp OOB lanes (j0>=80) to a
                // valid address — their XPT A-side is zero so product is 0.
                int j0c = (j0 < 80) ? j0 : 0;
                const f32x4* p = (const f32x4*)(awh + i * 80 + j0c);
                bf16x8 bfrag = cvt8(p[0], p[1]);
                // A-frags from XPT rows c = 32h + d
                bf16x8 a0 = *(const bf16x8*)(lds + (h * 32 + l16) * XPT_STRIDE + j0 * 2);
                bf16x8 a1 = *(const bf16x8*)(lds + (h * 32 + 16 + l16) * XPT_STRIDE + j0 * 2);
                acc[0][n4] = __builtin_amdgcn_mfma_f32_16x16x32_bf16(a0, bfrag, acc[0][n4], 0, 0, 0);
                acc[1][n4] = __builtin_amdgcn_mfma_f32_16x16x32_bf16(a1, bfrag, acc[1][n4], 0, 0, 0);
            }
        }
        // epilogue: ATT[i][c] for c-chunk of head h, into region(h).
        // C-frag: rows d = md*16 + q*4 + r, col i = n4*16 + l16.
        #pragma unroll
        for (int n4 = 0; n4 < 4; ++n4) {
            int i = n4 * 16 + l16;
            #pragma unroll
            for (int md = 0; md < 2; ++md) {
                bf16x4 w4;
                #pragma unroll
                for (int r = 0; r < 4; ++r)
                    w4[r] = (__bf16)acc[md][n4][r];
                int d0 = md * 16 + q * 4;
                *(bf16x4*)(lds + h * REG_SIZE + i * REG_STRIDE + d0 * 2) = w4;
            }
        }
    }

    __syncthreads();

    // =========== Phase 3: FIN[i][e] = ATT[i][:] @ W_out + b_out =============
    // M = 64 (4 m-tiles), N = 64 cols/wave (4 n-tiles), K = 256 (8 chunks,
    // chunk kc lives in head region kc).
    #pragma unroll
    for (int mt = 0; mt < 4; ++mt) {
        bf16x8 af[8];
        #pragma unroll
        for (int kc = 0; kc < 8; ++kc)
            af[kc] = *(const bf16x8*)(lds + kc * REG_SIZE +
                                      (mt * 16 + l16) * REG_STRIDE + q * 16);
        #pragma unroll
        for (int n4 = 0; n4 < 4; ++n4) {
            int e = nbase + n4 * 16 + l16;
            f32x4 acc = {0.f, 0.f, 0.f, 0.f};
            const __bf16* wcol = WoT + e * 256 + q * 8;
            #pragma unroll
            for (int kc = 0; kc < 8; ++kc) {
                bf16x8 bfrag = *(const bf16x8*)(wcol + kc * 32);
                acc = __builtin_amdgcn_mfma_f32_16x16x32_bf16(af[kc], bfrag, acc, 0, 0, 0);
            }
            float bias = b_out[e];
            #pragma unroll
            for (int r = 0; r < 4; ++r) {
                int ie  = mt * 16 + q * 4 + r;
                int tok = ((bh << 3) + (ie >> 3)) * 128 + (bw << 3) + (ie & 7);
                out[((size_t)b * 16384 + tok) * 256 + e] = acc[r] + bias;
            }
        }
    }
}

extern "C" void kernel_launch(void* const* d_in, const int* in_sizes, int n_in,
                              void* d_out, int out_size, void* d_ws, size_t ws_size,
                              hipStream_t stream) {
    (void)in_sizes; (void)n_in; (void)out_size; (void)ws_size;
    const float* x   = (const float*)d_in[0];
    const float* aw  = (const float*)d_in[1];
    const int*   idx = (const int*)d_in[2];
    const float* wts = (const float*)d_in[3];
    const float* Wi  = (const float*)d_in[4];
    const float* bi  = (const float*)d_in[5];
    const float* Wo  = (const float*)d_in[6];
    const float* bo  = (const float*)d_in[7];

    __bf16* WiT = (__bf16*)d_ws;          // 256*256 bf16 = 128 KB
    __bf16* WoT = WiT + 256 * 256;        // next 128 KB
    float*  o   = (float*)d_out;

    prep_weights_k<<<dim3(256), dim3(256), 0, stream>>>(Wi, Wo, WiT, WoT);
    fused_attn_k<<<dim3(2048), dim3(256), 0, stream>>>(
        x, aw, idx, wts, bi, bo, WiT, WoT, o);
}

// Round 2
// 817.205 us; speedup vs baseline: 1.0839x; 1.0839x over previous
//
#include <hip/hip_runtime.h>

// ---------------------------------------------------------------------------
// SelfAttention block-sparse value aggregation, fully fused, bf16 MFMA.
// B=8, H=W=128, E=256, VD=256, nh=8, vhd=32, bs=8 (bs2=64), topk=16.
// One workgroup (256 thr = 4 waves) per (batch, block) tile; 2048 WGs.
// R2: LDS 52KB->40KB (4 WG/CU), K-pad via register-zeroed A-frags,
//     phase-2 A-frag hoist + double-buffered aw prefetch, launch_bounds(256,4).
// LDS: XPT[256 cols][80 tokens] bf16 (stride 160B); per-head ATT region
// (5120B, stride 80B) aliases exactly that head's 32 XPT rows, written by the
// same wave after its reads complete -> single __syncthreads() in kernel.
// ---------------------------------------------------------------------------

typedef __attribute__((ext_vector_type(4))) float   f32x4;
typedef __attribute__((ext_vector_type(8))) __bf16  bf16x8;
typedef __attribute__((ext_vector_type(4))) __bf16  bf16x4;

#define XPT_STRIDE 160   // bytes per XPT row (80 bf16 elems, no pad)
#define REG_SIZE   5120  // bytes per head ATT region (= 32*XPT_STRIDE)
#define REG_STRIDE 80    // bytes per ATT region row (40 bf16 elems, 32 used)
#define LDS_BYTES  40960 // 256 * 160 -> 4 WG/CU

__global__ void prep_weights_k(const float* __restrict__ Wi,
                               const float* __restrict__ Wo,
                               __bf16* __restrict__ WiT,
                               __bf16* __restrict__ WoT) {
    int n = blockIdx.x;   // 256
    int k = threadIdx.x;  // 256
    WiT[n * 256 + k] = (__bf16)Wi[k * 256 + n];   // WiT[n][k] = W_in[k][n]
    WoT[n * 256 + k] = (__bf16)Wo[k * 256 + n];   // WoT[e][c] = W_out[c][e]
}

__device__ __forceinline__ bf16x8 cvt8(f32x4 lo, f32x4 hi) {
    bf16x8 r;
    r[0] = (__bf16)lo.x; r[1] = (__bf16)lo.y; r[2] = (__bf16)lo.z; r[3] = (__bf16)lo.w;
    r[4] = (__bf16)hi.x; r[5] = (__bf16)hi.y; r[6] = (__bf16)hi.z; r[7] = (__bf16)hi.w;
    return r;
}

__global__ __launch_bounds__(256, 4) void fused_attn_k(
    const float* __restrict__ x,     // (8,128,128,256) f32
    const float* __restrict__ aw,    // (8,8,256,64,80) f32
    const int*   __restrict__ idx,   // (8,256,16) i32
    const float* __restrict__ wts,   // (8,256,16) f32
    const float* __restrict__ b_in,  // (256) f32
    const float* __restrict__ b_out, // (256) f32
    const __bf16* __restrict__ WiT,  // (256,256) bf16 [n][k]
    const __bf16* __restrict__ WoT,  // (256,256) bf16 [e][c]
    float* __restrict__ out)         // (8,128,128,256) f32
{
    __shared__ __align__(16) unsigned char lds[LDS_BYTES];

    const int tid  = threadIdx.x;
    const int lane = tid & 63;
    const int wv   = tid >> 6;       // 0..3
    const int l16  = lane & 15;
    const int q    = lane >> 4;      // 0..3
    const int bid  = blockIdx.x;
    const int b    = bid >> 8;       // batch
    const int blk  = bid & 255;      // block id
    const int bh   = blk >> 4, bw = blk & 15;
    const int nbase = wv * 64;       // this wave's vd-column quarter

    const float* xb   = x   + (size_t)b * 16384 * 256;
    const int*   idxb = idx + (b * 256 + blk) * 16;
    const float* wtsb = wts + (b * 256 + blk) * 16;

    // =========== Phase 1: XPT[c][j] = (x_row_j . W_in[:,c] + b_in[c]) * rs ==
    // M = 80 tokens (5 m-tiles), N = 64 cols/wave (4 n-tiles), K = 256 (8 ch)
    for (int mt = 0; mt < 5; ++mt) {
        // A-operand row for this lane: token m = mt*16 + l16
        int m = mt * 16 + l16;
        int tokA;
        if (m < 64) {
            tokA = ((bh << 3) + (m >> 3)) * 128 + (bw << 3) + (m & 7);
        } else {
            tokA = idxb[m - 64];
        }
        const float* xrow = xb + (size_t)tokA * 256;
        bf16x8 af[8];
        #pragma unroll
        for (int kc = 0; kc < 8; ++kc) {
            const f32x4* p = (const f32x4*)(xrow + kc * 32 + q * 8);
            af[kc] = cvt8(p[0], p[1]);
        }
        // row scales for the 4 C-frag rows (gathered tokens get their weight)
        float rs[4];
        #pragma unroll
        for (int r = 0; r < 4; ++r) {
            int me = mt * 16 + q * 4 + r;
            rs[r] = (me >= 64) ? wtsb[me - 64] : 1.0f;
        }
        const int j0w = mt * 16 + q * 4;  // epilogue token base
        #pragma unroll
        for (int n4 = 0; n4 < 4; ++n4) {
            int c = nbase + n4 * 16 + l16;
            f32x4 acc = {0.f, 0.f, 0.f, 0.f};
            const __bf16* wcol = WiT + c * 256 + q * 8;
            #pragma unroll
            for (int kc = 0; kc < 8; ++kc) {
                bf16x8 bfrag = *(const bf16x8*)(wcol + kc * 32);
                acc = __builtin_amdgcn_mfma_f32_16x16x32_bf16(af[kc], bfrag, acc, 0, 0, 0);
            }
            float bias = b_in[c];
            bf16x4 w4;
            #pragma unroll
            for (int r = 0; r < 4; ++r)
                w4[r] = (__bf16)((acc[r] + bias) * rs[r]);
            // XPT[c][j0w .. j0w+3]
            *(bf16x4*)(lds + c * XPT_STRIDE + j0w * 2) = w4;
        }
    }

    // =========== Phase 2: attention, transposed: OUT^T[d][i] ================
    // per head: M = d (32, 2 tiles), N = i (64, 4 tiles), K = j (80, pad 96
    // via register-zeroed A-frags). Double-buffered aw prefetch over kc.
    #pragma unroll
    for (int hh = 0; hh < 2; ++hh) {
        const int h = wv * 2 + hh;
        const float* awh = aw + ((size_t)(h * 8 + b) * 256 + blk) * (64 * 80);
        const float* awl = awh + l16 * 80;    // this lane's base query row
        f32x4 acc[2][4];
        #pragma unroll
        for (int md = 0; md < 2; ++md)
            #pragma unroll
            for (int n4 = 0; n4 < 4; ++n4)
                acc[md][n4] = (f32x4){0.f, 0.f, 0.f, 0.f};

        // preload kc=0 B-chunks: aw[i][q*8 .. q*8+7] for i = n4*16 + l16
        f32x4 pb[4][2];
        #pragma unroll
        for (int n4 = 0; n4 < 4; ++n4) {
            const f32x4* p = (const f32x4*)(awl + n4 * (16 * 80) + q * 8);
            pb[n4][0] = p[0]; pb[n4][1] = p[1];
        }

        #pragma unroll
        for (int kc = 0; kc < 3; ++kc) {
            // prefetch next kc's B-chunks while this kc computes
            f32x4 nb[4][2];
            if (kc < 2) {
                int j0n = (kc + 1) * 32 + q * 8;
                int j0c = (j0n < 80) ? j0n : 0;   // clamp OOB lanes (A is 0)
                #pragma unroll
                for (int n4 = 0; n4 < 4; ++n4) {
                    const f32x4* p = (const f32x4*)(awl + n4 * (16 * 80) + j0c);
                    nb[n4][0] = p[0]; nb[n4][1] = p[1];
                }
            }
            // A-frags from XPT rows c = 32h + d (shared across n4)
            int j0  = kc * 32 + q * 8;
            int j0a = (j0 < 80) ? j0 : 0;
            bf16x8 a0 = *(const bf16x8*)(lds + (h * 32 + l16) * XPT_STRIDE + j0a * 2);
            bf16x8 a1 = *(const bf16x8*)(lds + (h * 32 + 16 + l16) * XPT_STRIDE + j0a * 2);
            if (j0 >= 80) {
                bf16x8 z = {};
                a0 = z; a1 = z;
            }
            #pragma unroll
            for (int n4 = 0; n4 < 4; ++n4) {
                bf16x8 bfrag = cvt8(pb[n4][0], pb[n4][1]);
                acc[0][n4] = __builtin_amdgcn_mfma_f32_16x16x32_bf16(a0, bfrag, acc[0][n4], 0, 0, 0);
                acc[1][n4] = __builtin_amdgcn_mfma_f32_16x16x32_bf16(a1, bfrag, acc[1][n4], 0, 0, 0);
            }
            if (kc < 2) {
                #pragma unroll
                for (int n4 = 0; n4 < 4; ++n4) {
                    pb[n4][0] = nb[n4][0]; pb[n4][1] = nb[n4][1];
                }
            }
        }

        // epilogue: ATT[i][c] for c-chunk of head h, into region(h) which
        // aliases this head's (already fully read) XPT rows.
        // C-frag: rows d = md*16 + q*4 + r, col i = n4*16 + l16.
        #pragma unroll
        for (int n4 = 0; n4 < 4; ++n4) {
            int i = n4 * 16 + l16;
            #pragma unroll
            for (int md = 0; md < 2; ++md) {
                bf16x4 w4;
                #pragma unroll
                for (int r = 0; r < 4; ++r)
                    w4[r] = (__bf16)acc[md][n4][r];
                int d0 = md * 16 + q * 4;
                *(bf16x4*)(lds + h * REG_SIZE + i * REG_STRIDE + d0 * 2) = w4;
            }
        }
    }

    __syncthreads();

    // =========== Phase 3: FIN[i][e] = ATT[i][:] @ W_out + b_out =============
    // M = 64 (4 m-tiles), N = 64 cols/wave (4 n-tiles), K = 256 (8 chunks,
    // chunk kc lives in head region kc).
    #pragma unroll
    for (int mt = 0; mt < 4; ++mt) {
        bf16x8 af[8];
        #pragma unroll
        for (int kc = 0; kc < 8; ++kc)
            af[kc] = *(const bf16x8*)(lds + kc * REG_SIZE +
                                      (mt * 16 + l16) * REG_STRIDE + q * 16);
        #pragma unroll
        for (int n4 = 0; n4 < 4; ++n4) {
            int e = nbase + n4 * 16 + l16;
            f32x4 acc = {0.f, 0.f, 0.f, 0.f};
            const __bf16* wcol = WoT + e * 256 + q * 8;
            #pragma unroll
            for (int kc = 0; kc < 8; ++kc) {
                bf16x8 bfrag = *(const bf16x8*)(wcol + kc * 32);
                acc = __builtin_amdgcn_mfma_f32_16x16x32_bf16(af[kc], bfrag, acc, 0, 0, 0);
            }
            float bias = b_out[e];
            #pragma unroll
            for (int r = 0; r < 4; ++r) {
                int ie  = mt * 16 + q * 4 + r;
                int tok = ((bh << 3) + (ie >> 3)) * 128 + (bw << 3) + (ie & 7);
                out[((size_t)b * 16384 + tok) * 256 + e] = acc[r] + bias;
            }
        }
    }
}

extern "C" void kernel_launch(void* const* d_in, const int* in_sizes, int n_in,
                              void* d_out, int out_size, void* d_ws, size_t ws_size,
                              hipStream_t stream) {
    (void)in_sizes; (void)n_in; (void)out_size; (void)ws_size;
    const float* x   = (const float*)d_in[0];
    const float* aw  = (const float*)d_in[1];
    const int*   idx = (const int*)d_in[2];
    const float* wts = (const float*)d_in[3];
    const float* Wi  = (const float*)d_in[4];
    const float* bi  = (const float*)d_in[5];
    const float* Wo  = (const float*)d_in[6];
    const float* bo  = (const float*)d_in[7];

    __bf16* WiT = (__bf16*)d_ws;          // 256*256 bf16 = 128 KB
    __bf16* WoT = WiT + 256 * 256;        // next 128 KB
    float*  o   = (float*)d_out;

    prep_weights_k<<<dim3(256), dim3(256), 0, stream>>>(Wi, Wo, WiT, WoT);
    fused_attn_k<<<dim3(2048), dim3(256), 0, stream>>>(
        x, aw, idx, wts, bi, bo, WiT, WoT, o);
}